// Round 5
// baseline (187.241 us; speedup 1.0000x reference)
//
#include <hip/hip_runtime.h>

// Problem constants (fixed by setup_inputs in the reference):
//   feature_map: (1, 256, 256, 256) fp32, NHWC   (67 MB)
//   rois:        (2000, 5) int32  [batch, x, y, w, h]
//   pool_size:   7
#define FH 256
#define FW 256
#define FC 256
#define POOL 7
#define CELLS_PER_ROI (POOL * POOL)   // 49
#define CPW 4                          // cells per wave

typedef float f32x4 __attribute__((ext_vector_type(4)));

// ---------------------------------------------------------------------------
// Pass 1: spatial counting-sort of ROI indices by 16x16-px tile of ROI center.
// Any permutation is correct (we index through perm and write to original
// output slots), so the non-deterministic intra-bucket atomic order is fine.
// Single block, 256 threads; writes perm[n_rois] into d_ws.
// ---------------------------------------------------------------------------
#define N_BUCKETS 256
__global__ __launch_bounds__(256) void roi_sort_kernel(
    const int* __restrict__ rois, int* __restrict__ perm, int n_rois)
{
    __shared__ int hist[N_BUCKETS];
    __shared__ int base[N_BUCKETS];
    __shared__ unsigned char keys[2048];
    int t = threadIdx.x;
    if (t < N_BUCKETS) hist[t] = 0;
    __syncthreads();
    for (int i = t; i < n_rois; i += blockDim.x) {
        int x = rois[i * 5 + 1], y = rois[i * 5 + 2];
        int w = rois[i * 5 + 3], h = rois[i * 5 + 4];
        int cx = x + (w >> 1), cy = y + (h >> 1);
        int key = (((cy >> 4) & 15) << 4) | ((cx >> 4) & 15);
        keys[i] = (unsigned char)key;
        atomicAdd(&hist[key], 1);
    }
    __syncthreads();
    if (t == 0) {                       // 256-entry exclusive prefix — trivial
        int acc = 0;
        for (int b = 0; b < N_BUCKETS; ++b) { base[b] = acc; acc += hist[b]; }
    }
    __syncthreads();
    if (t < N_BUCKETS) hist[t] = 0;
    __syncthreads();
    for (int i = t; i < n_rois; i += blockDim.x) {
        int key = keys[i];
        int pos = base[key] + atomicAdd(&hist[key], 1);
        perm[pos] = i;
    }
}

// ---------------------------------------------------------------------------
// Pass 2: one wave per CPW consecutive cells IN SORTED ROI ORDER; 64 lanes x
// float4 = 256 channels. Inverse-XCD swizzle keeps each XCD's share of the
// sorted order contiguous -> each XCD works a spatially compact fm strip that
// fits its 4 MB L2, converting the ~40x cross-ROI pixel reuse into L2 hits.
// Output written to ORIGINAL roi slots (perm lookup), NT stores (write-once).
// ---------------------------------------------------------------------------
__global__ __launch_bounds__(256) void roi_pool_kernel(
    const float* __restrict__ fm,
    const int*   __restrict__ rois,
    const int*   __restrict__ perm,
    float*       __restrict__ out,
    int n_cells, int chunk)
{
    int b  = blockIdx.x;
    int lb = (b & 7) * chunk + (b >> 3);   // logical block, contiguous per XCD

    int lane = threadIdx.x & 63;
    int wave = threadIdx.x >> 6;
    int base_cell = __builtin_amdgcn_readfirstlane((lb * 4 + wave) * CPW);
    if (base_cell >= n_cells) return;      // n_cells % CPW == 0

    f32x4 A[CPW], B[CPW], C[CPW], D[CPW];
    float WX[CPW], WY[CPW];
    int   OROI[CPW], SUB[CPW];

#pragma unroll
    for (int c = 0; c < CPW; ++c) {
        int cell = base_cell + c;              // wave-uniform
        int sorted_pos = cell / CELLS_PER_ROI;
        int sub        = cell % CELLS_PER_ROI;
        int roi  = perm[sorted_pos];           // original ROI index
        OROI[c] = roi; SUB[c] = sub;
        int pi = sub % POOL;
        int pj = sub / POOL;

        int rx = rois[roi * 5 + 1];
        int ry = rois[roi * 5 + 2];
        int rw = rois[roi * 5 + 3];
        int rh = rois[roi * 5 + 4];

        // Half-pixel-center bilinear coords of crop resize (matches ref).
        float lfh = (float)rh;
        float fy  = ((float)pj + 0.5f) * (lfh / (float)POOL) - 0.5f;
        fy = fminf(fmaxf(fy, 0.0f), lfh - 1.0f);
        int   j0 = (int)floorf(fy);
        int   j1 = min(j0 + 1, rh - 1);
        WY[c] = fy - (float)j0;
        int   y0 = ry + j0;
        int   y1 = ry + j1;

        float lfw = (float)rw;
        float fx  = ((float)pi + 0.5f) * (lfw / (float)POOL) - 0.5f;
        fx = fminf(fmaxf(fx, 0.0f), lfw - 1.0f);
        int   i0 = (int)floorf(fx);
        int   i1 = min(i0 + 1, rw - 1);
        WX[c] = fx - (float)i0;
        int   x0 = rx + i0;
        int   x1 = rx + i1;

        A[c] = *((const f32x4*)(fm + ((size_t)y0 * FW + x0) * FC) + lane);
        B[c] = *((const f32x4*)(fm + ((size_t)y0 * FW + x1) * FC) + lane);
        C[c] = *((const f32x4*)(fm + ((size_t)y1 * FW + x0) * FC) + lane);
        D[c] = *((const f32x4*)(fm + ((size_t)y1 * FW + x1) * FC) + lane);
    }

#pragma unroll
    for (int c = 0; c < CPW; ++c) {
        float wx = WX[c], wy = WY[c];
        float owx = 1.0f - wx, owy = 1.0f - wy;
        f32x4 r = (A[c] * owx + B[c] * wx) * owy
                + (C[c] * owx + D[c] * wx) * wy;
        size_t ocell = (size_t)OROI[c] * CELLS_PER_ROI + SUB[c];
        f32x4* o = (f32x4*)(out + ocell * FC) + lane;
        __builtin_nontemporal_store(r, o);     // write-once stream
    }
}

extern "C" void kernel_launch(void* const* d_in, const int* in_sizes, int n_in,
                              void* d_out, int out_size, void* d_ws, size_t ws_size,
                              hipStream_t stream) {
    const float* fm   = (const float*)d_in[0];
    const int*   rois = (const int*)d_in[1];
    // d_in[2] is pool_size (==7), fixed by the problem; hardcoded as POOL.
    float* out  = (float*)d_out;
    int*   perm = (int*)d_ws;              // n_rois ints of scratch

    int n_rois  = in_sizes[1] / 5;
    int n_cells = n_rois * CELLS_PER_ROI;            // 98000 (divisible by CPW)
    int n_waves = (n_cells + CPW - 1) / CPW;         // 24500
    int blocks  = (n_waves + 3) / 4;                 // 4 waves/block -> 6125
    blocks      = (blocks + 7) & ~7;                 // pad to x8 -> 6128
    int chunk   = blocks / 8;                        // logical blocks per XCD

    roi_sort_kernel<<<1, 256, 0, stream>>>(rois, perm, n_rois);
    roi_pool_kernel<<<blocks, 256, 0, stream>>>(fm, rois, perm, out,
                                                n_cells, chunk);
}